// Round 4
// baseline (488.928 us; speedup 1.0000x reference)
//
#include <hip/hip_runtime.h>
#include <hip/hip_fp16.h>

// EncConvNet fused v3.1 (v3 with the w2b LDS-overflow bug fixed).
//  - h stored fp16 + XOR-swizzled: slot = k4*64 + (img ^ (k4&15)) puts the
//    per-lane k4 into the bank bits -> kills the 64-way conflict on the conv
//    h-store that cost v2 12.6M conflict cycles.
//  - LDS 60.5 KB (fp16 h, single-buffered x stage, h2/out aliased into the
//    dead x buffer) -> 2 blocks/CU = 16 waves/CU so barrier stalls overlap
//    across independent blocks.
//  - BUGFIX vs v3: w2b is indexed kk*16+j (kk<16, j<10) -> needs 1000 floats;
//    v3 allocated 256 -> staging wrote past the dynamic-LDS extent -> fc2
//    read garbage (absmax 5.09). Now 1024 floats.

#define BLK_IMGS    64
#define CHUNK_IMGS  8
#define NCHUNK      8
#define XCH_FLOATS  (CHUNK_IMGS * 784)   // 6272 floats = 25088 B

// LDS float offsets
#define LDS_XBUF    0                     // 6272 floats (aliased later: h2 16KB, out)
#define LDS_H_F     6272                  // h: 64 slots * 64 imgs * 8B = 32768 B
#define LDS_W2_F    (6272 + 8192)         // fc2 weights: kk*16+j slots -> 1000 floats used
#define LDS_TOTAL_F (6272 + 8192 + 1024)  // 15488 floats = 61952 B

union h2cvt { __half2 h; unsigned int u; };

__global__ __launch_bounds__(512, 4)
void encconv_fused3(const float* __restrict__ x,
                    const float* __restrict__ conv_w,
                    const float* __restrict__ conv_b,
                    const float* __restrict__ fc1_w,
                    const float* __restrict__ fc1_b,
                    const float* __restrict__ fc2_w,
                    const float* __restrict__ fc2_b,
                    float* __restrict__ out)
{
    extern __shared__ float lds[];
    float*  xbuf = lds + LDS_XBUF;
    uint2*  hbuf = (uint2*)(lds + LDS_H_F);        // fp16 h, swizzled
    float4* w2b  = (float4*)(lds + LDS_W2_F);
    float4* h2b  = (float4*)(lds + LDS_XBUF);      // alias: 16KB of xbuf
    float*  ob   = lds + 4096;                     // alias: xbuf floats 4096..4735

    const int tid = threadIdx.x;
    const int blk = blockIdx.x;
    const long base_img = (long)blk * BLK_IMGS;

    // conv-phase roles: tid = g*64 + y*8 + c*2 + xh  (wave g = image-in-chunk)
    const int g  = tid >> 6;
    const int y  = (tid >> 3) & 7;
    const int c  = (tid >> 1) & 3;
    const int xh = tid & 1;
    const int k4 = c * 16 + y * 2 + xh;   // per-lane 0..63
    const int sw = (y * 2 + xh) & 15;     // = k4 & 15 (swizzle bits)

    // per-lane conv taps (L1-broadcast, one-time)
    float wv[49];
    #pragma unroll
    for (int i = 0; i < 49; ++i) wv[i] = conv_w[c * 49 + i];
    const float cb = conv_b[c];

    // stage fc2_w into LDS, k-major: slot = kk*16 + j
    if (tid < 160) {
        float4 v = *(const float4*)(fc2_w + tid * 4);
        int e  = tid * 4;
        int j  = e >> 6;
        int kk = (e & 63) >> 2;
        w2b[kk * 16 + j] = v;
    }

    const float* xblk = x + base_img * 784;

    // prefetch chunk 0 (coalesced register prefetch)
    float4 pf0, pf1, pf2, pf3;
    {
        const float* src = xblk;
        pf0 = *(const float4*)(src + 4 * tid);
        pf1 = *(const float4*)(src + 4 * (tid + 512));
        pf2 = *(const float4*)(src + 4 * (tid + 1024));
        if (tid < 32) pf3 = *(const float4*)(src + 4 * (tid + 1536));
    }

    for (int ch = 0; ch < NCHUNK; ++ch) {
        if (ch > 0) __syncthreads();          // prior chunk's x reads done
        *(float4*)(xbuf + 4 * tid)          = pf0;
        *(float4*)(xbuf + 4 * (tid + 512))  = pf1;
        *(float4*)(xbuf + 4 * (tid + 1024)) = pf2;
        if (tid < 32) *(float4*)(xbuf + 4 * (tid + 1536)) = pf3;
        __syncthreads();

        if (ch + 1 < NCHUNK) {                // latency hidden by conv below
            const float* src = xblk + (ch + 1) * XCH_FLOATS;
            pf0 = *(const float4*)(src + 4 * tid);
            pf1 = *(const float4*)(src + 4 * (tid + 512));
            pf2 = *(const float4*)(src + 4 * (tid + 1024));
            if (tid < 32) pf3 = *(const float4*)(src + 4 * (tid + 1536));
        }

        // conv: image g, row y, channel c, output cols 4xh..4xh+3
        float acc0 = 0.f, acc1 = 0.f, acc2 = 0.f, acc3 = 0.f;
        const float* xi = xbuf + g * 784;
        #pragma unroll
        for (int rr = 0; rr < 7; ++rr) {
            const float* rp = xi + (3 * y + rr) * 28 + 12 * xh;
            float4 r0 = *(const float4*)(rp + 0);
            float4 r1 = *(const float4*)(rp + 4);
            float4 r2 = *(const float4*)(rp + 8);
            float4 r3 = *(const float4*)(rp + 12);
            float r[16] = { r0.x, r0.y, r0.z, r0.w,
                            r1.x, r1.y, r1.z, r1.w,
                            r2.x, r2.y, r2.z, r2.w,
                            r3.x, r3.y, r3.z, r3.w };
            #pragma unroll
            for (int kx = 0; kx < 7; ++kx) {
                const float w = wv[rr * 7 + kx];
                acc0 = fmaf(r[0 + kx], w, acc0);
                acc1 = fmaf(r[3 + kx], w, acc1);
                acc2 = fmaf(r[6 + kx], w, acc2);
                acc3 = fmaf(r[9 + kx], w, acc3);
            }
        }

        // bias + square -> fp16, swizzled b64 store
        float h0 = acc0 + cb; h0 *= h0;
        float h1 = acc1 + cb; h1 *= h1;
        float h2v_ = acc2 + cb; h2v_ *= h2v_;
        float h3 = acc3 + cb; h3 *= h3;
        h2cvt lo, hi;
        lo.h = __floats2half2_rn(h0, h1);
        hi.h = __floats2half2_rn(h2v_, h3);
        const int img = ch * CHUNK_IMGS + g;
        hbuf[(k4 << 6) + (img ^ sw)] = make_uint2(lo.u, hi.u);
    }
    __syncthreads();

    // ---- fc1: wave w8 -> outputs 8*w8..8*w8+7, lanes = 64 images ----
    {
        const int img = tid & 63;
        const int w8  = __builtin_amdgcn_readfirstlane(tid >> 6);
        const float* wbase = fc1_w + (w8 * 8) * 256;

        float a0=0.f,a1=0.f,a2=0.f,a3=0.f,a4=0.f,a5=0.f,a6=0.f,a7=0.f;

        #pragma unroll 2
        for (int kk = 0; kk < 64; ++kk) {
            uint2 hu = hbuf[(kk << 6) + (img ^ (kk & 15))];   // perm-contiguous b64
            h2cvt ua, ub; ua.u = hu.x; ub.u = hu.y;
            float2 f01 = __half22float2(ua.h);
            float2 f23 = __half22float2(ub.h);
            const float* wp = wbase + kk * 4;
            float4 w0 = *(const float4*)(wp + 0 * 256);   // uniform -> s_load
            float4 w1 = *(const float4*)(wp + 1 * 256);
            float4 w2 = *(const float4*)(wp + 2 * 256);
            float4 w3 = *(const float4*)(wp + 3 * 256);
            float4 w4 = *(const float4*)(wp + 4 * 256);
            float4 w5 = *(const float4*)(wp + 5 * 256);
            float4 w6 = *(const float4*)(wp + 6 * 256);
            float4 w7 = *(const float4*)(wp + 7 * 256);
            a0 = fmaf(f01.x,w0.x,a0); a0 = fmaf(f01.y,w0.y,a0); a0 = fmaf(f23.x,w0.z,a0); a0 = fmaf(f23.y,w0.w,a0);
            a1 = fmaf(f01.x,w1.x,a1); a1 = fmaf(f01.y,w1.y,a1); a1 = fmaf(f23.x,w1.z,a1); a1 = fmaf(f23.y,w1.w,a1);
            a2 = fmaf(f01.x,w2.x,a2); a2 = fmaf(f01.y,w2.y,a2); a2 = fmaf(f23.x,w2.z,a2); a2 = fmaf(f23.y,w2.w,a2);
            a3 = fmaf(f01.x,w3.x,a3); a3 = fmaf(f01.y,w3.y,a3); a3 = fmaf(f23.x,w3.z,a3); a3 = fmaf(f23.y,w3.w,a3);
            a4 = fmaf(f01.x,w4.x,a4); a4 = fmaf(f01.y,w4.y,a4); a4 = fmaf(f23.x,w4.z,a4); a4 = fmaf(f23.y,w4.w,a4);
            a5 = fmaf(f01.x,w5.x,a5); a5 = fmaf(f01.y,w5.y,a5); a5 = fmaf(f23.x,w5.z,a5); a5 = fmaf(f23.y,w5.w,a5);
            a6 = fmaf(f01.x,w6.x,a6); a6 = fmaf(f01.y,w6.y,a6); a6 = fmaf(f23.x,w6.z,a6); a6 = fmaf(f23.y,w6.w,a6);
            a7 = fmaf(f01.x,w7.x,a7); a7 = fmaf(f01.y,w7.y,a7); a7 = fmaf(f23.x,w7.z,a7); a7 = fmaf(f23.y,w7.w,a7);
        }

        __syncthreads();   // everyone past conv-phase xbuf use before h2 aliases it

        const float* bp = fc1_b + w8 * 8;
        float4 p0, p1;
        p0.x = a0 + bp[0]; p0.x *= p0.x;
        p0.y = a1 + bp[1]; p0.y *= p0.y;
        p0.z = a2 + bp[2]; p0.z *= p0.z;
        p0.w = a3 + bp[3]; p0.w *= p0.w;
        p1.x = a4 + bp[4]; p1.x *= p1.x;
        p1.y = a5 + bp[5]; p1.y *= p1.y;
        p1.z = a6 + bp[6]; p1.z *= p1.z;
        p1.w = a7 + bp[7]; p1.w *= p1.w;
        h2b[(w8 * 2 + 0) * 64 + img] = p0;   // lane-contiguous b128
        h2b[(w8 * 2 + 1) * 64 + img] = p1;
    }
    __syncthreads();

    // ---- fc2: thread (im3 = tid>>3, q = tid&7) ----
    {
        const int im3 = tid >> 3;
        const int q   = tid & 7;

        float s1 = 0.f;
        #pragma unroll
        for (int kk = 0; kk < 16; ++kk) {
            float4 hh = h2b[kk * 64 + im3];
            float4 wA = w2b[kk * 16 + q];
            s1 = fmaf(hh.x, wA.x, s1); s1 = fmaf(hh.y, wA.y, s1);
            s1 = fmaf(hh.z, wA.z, s1); s1 = fmaf(hh.w, wA.w, s1);
        }
        float r1 = s1 + fc2_b[q];

        float r2 = 0.f;
        if (q < 2) {
            float s2 = 0.f;
            #pragma unroll
            for (int kk = 0; kk < 16; ++kk) {
                float4 hh = h2b[kk * 64 + im3];
                float4 wB = w2b[kk * 16 + 8 + q];
                s2 = fmaf(hh.x, wB.x, s2); s2 = fmaf(hh.y, wB.y, s2);
                s2 = fmaf(hh.z, wB.z, s2); s2 = fmaf(hh.w, wB.w, s2);
            }
            r2 = s2 + fc2_b[8 + q];
        }
        __syncthreads();               // h2 reads done before ob overwrites region? (no overlap, but keeps ordering simple)
        ob[im3 * 10 + q] = r1;
        if (q < 2) ob[im3 * 10 + 8 + q] = r2;
    }
    __syncthreads();

    // coalesced output store
    if (tid < 160) {
        float4 v = *(const float4*)(ob + tid * 4);
        *(float4*)(out + (long)blk * 640 + tid * 4) = v;
    }
}

extern "C" void kernel_launch(void* const* d_in, const int* in_sizes, int n_in,
                              void* d_out, int out_size, void* d_ws, size_t ws_size,
                              hipStream_t stream) {
    const float* x      = (const float*)d_in[0];
    const float* conv_w = (const float*)d_in[1];
    const float* conv_b = (const float*)d_in[2];
    const float* fc1_w  = (const float*)d_in[3];
    const float* fc1_b  = (const float*)d_in[4];
    const float* fc2_w  = (const float*)d_in[5];
    const float* fc2_b  = (const float*)d_in[6];
    float* out = (float*)d_out;

    const int B = in_sizes[0] / 784;
    const int blocks = (B + BLK_IMGS - 1) / BLK_IMGS;      // 1024 for B=65536
    const size_t lds_bytes = LDS_TOTAL_F * sizeof(float);  // 61952

    static bool attr_set = false;
    if (!attr_set) {
        (void)hipFuncSetAttribute((const void*)encconv_fused3,
                                  hipFuncAttributeMaxDynamicSharedMemorySize,
                                  (int)lds_bytes);
        attr_set = true;
    }

    encconv_fused3<<<blocks, 512, lds_bytes, stream>>>(
        x, conv_w, conv_b, fc1_w, fc1_b, fc2_w, fc2_b, out);
}

// Round 5
// 362.172 us; speedup vs baseline: 1.3500x; 1.3500x over previous
//
#include <hip/hip_runtime.h>
#include <hip/hip_fp16.h>

// EncConvNet fused v4 = v3.1 with the register-spill regression fixed.
//  - __launch_bounds__(512, 2): the (512,4) cap in v3.1 forced VGPR=64 and
//    spilled wv[49]+prefetch regs to scratch -> 680 MB of HBM spill traffic
//    (FETCH 506 MB / WRITE 282 MB, dur 290us). v2 compiled this pressure at
//    128 VGPRs cleanly; 128 VGPR + 60.5 KB LDS still fits 2 blocks/CU.
//  - LDS 61952 B < 64 KB default cap -> no hipFuncSetAttribute needed.
//  - Everything else identical to the passing v3.1 (absmax 0.031).

#define BLK_IMGS    64
#define CHUNK_IMGS  8
#define NCHUNK      8
#define XCH_FLOATS  (CHUNK_IMGS * 784)   // 6272 floats = 25088 B

// LDS float offsets
#define LDS_XBUF    0                     // 6272 floats (aliased later: h2 16KB, out)
#define LDS_H_F     6272                  // h: 64 slots * 64 imgs * 8B = 32768 B
#define LDS_W2_F    (6272 + 8192)         // fc2 weights: kk*16+j slots -> 1000 floats used
#define LDS_TOTAL_F (6272 + 8192 + 1024)  // 15488 floats = 61952 B

union h2cvt { __half2 h; unsigned int u; };

__global__ __launch_bounds__(512, 2)
void encconv_fused4(const float* __restrict__ x,
                    const float* __restrict__ conv_w,
                    const float* __restrict__ conv_b,
                    const float* __restrict__ fc1_w,
                    const float* __restrict__ fc1_b,
                    const float* __restrict__ fc2_w,
                    const float* __restrict__ fc2_b,
                    float* __restrict__ out)
{
    extern __shared__ float lds[];
    float*  xbuf = lds + LDS_XBUF;
    uint2*  hbuf = (uint2*)(lds + LDS_H_F);        // fp16 h, swizzled
    float4* w2b  = (float4*)(lds + LDS_W2_F);
    float4* h2b  = (float4*)(lds + LDS_XBUF);      // alias: 16KB of xbuf
    float*  ob   = lds + 4096;                     // alias: xbuf floats 4096..4735

    const int tid = threadIdx.x;
    const int blk = blockIdx.x;
    const long base_img = (long)blk * BLK_IMGS;

    // conv-phase roles: tid = g*64 + y*8 + c*2 + xh  (wave g = image-in-chunk)
    const int g  = tid >> 6;
    const int y  = (tid >> 3) & 7;
    const int c  = (tid >> 1) & 3;
    const int xh = tid & 1;
    const int k4 = c * 16 + y * 2 + xh;   // per-lane 0..63
    const int sw = (y * 2 + xh) & 15;     // = k4 & 15 (swizzle bits)

    // per-lane conv taps (L1-broadcast, one-time)
    float wv[49];
    #pragma unroll
    for (int i = 0; i < 49; ++i) wv[i] = conv_w[c * 49 + i];
    const float cb = conv_b[c];

    // stage fc2_w into LDS, k-major: slot = kk*16 + j
    if (tid < 160) {
        float4 v = *(const float4*)(fc2_w + tid * 4);
        int e  = tid * 4;
        int j  = e >> 6;
        int kk = (e & 63) >> 2;
        w2b[kk * 16 + j] = v;
    }

    const float* xblk = x + base_img * 784;

    // prefetch chunk 0 (coalesced register prefetch)
    float4 pf0, pf1, pf2, pf3;
    {
        const float* src = xblk;
        pf0 = *(const float4*)(src + 4 * tid);
        pf1 = *(const float4*)(src + 4 * (tid + 512));
        pf2 = *(const float4*)(src + 4 * (tid + 1024));
        if (tid < 32) pf3 = *(const float4*)(src + 4 * (tid + 1536));
    }

    for (int ch = 0; ch < NCHUNK; ++ch) {
        if (ch > 0) __syncthreads();          // prior chunk's x reads done
        *(float4*)(xbuf + 4 * tid)          = pf0;
        *(float4*)(xbuf + 4 * (tid + 512))  = pf1;
        *(float4*)(xbuf + 4 * (tid + 1024)) = pf2;
        if (tid < 32) *(float4*)(xbuf + 4 * (tid + 1536)) = pf3;
        __syncthreads();

        if (ch + 1 < NCHUNK) {                // latency hidden by conv below
            const float* src = xblk + (ch + 1) * XCH_FLOATS;
            pf0 = *(const float4*)(src + 4 * tid);
            pf1 = *(const float4*)(src + 4 * (tid + 512));
            pf2 = *(const float4*)(src + 4 * (tid + 1024));
            if (tid < 32) pf3 = *(const float4*)(src + 4 * (tid + 1536));
        }

        // conv: image g, row y, channel c, output cols 4xh..4xh+3
        float acc0 = 0.f, acc1 = 0.f, acc2 = 0.f, acc3 = 0.f;
        const float* xi = xbuf + g * 784;
        #pragma unroll
        for (int rr = 0; rr < 7; ++rr) {
            const float* rp = xi + (3 * y + rr) * 28 + 12 * xh;
            float4 r0 = *(const float4*)(rp + 0);
            float4 r1 = *(const float4*)(rp + 4);
            float4 r2 = *(const float4*)(rp + 8);
            float4 r3 = *(const float4*)(rp + 12);
            float r[16] = { r0.x, r0.y, r0.z, r0.w,
                            r1.x, r1.y, r1.z, r1.w,
                            r2.x, r2.y, r2.z, r2.w,
                            r3.x, r3.y, r3.z, r3.w };
            #pragma unroll
            for (int kx = 0; kx < 7; ++kx) {
                const float w = wv[rr * 7 + kx];
                acc0 = fmaf(r[0 + kx], w, acc0);
                acc1 = fmaf(r[3 + kx], w, acc1);
                acc2 = fmaf(r[6 + kx], w, acc2);
                acc3 = fmaf(r[9 + kx], w, acc3);
            }
        }

        // bias + square -> fp16, swizzled b64 store
        float h0 = acc0 + cb; h0 *= h0;
        float h1 = acc1 + cb; h1 *= h1;
        float h2v_ = acc2 + cb; h2v_ *= h2v_;
        float h3 = acc3 + cb; h3 *= h3;
        h2cvt lo, hi;
        lo.h = __floats2half2_rn(h0, h1);
        hi.h = __floats2half2_rn(h2v_, h3);
        const int img = ch * CHUNK_IMGS + g;
        hbuf[(k4 << 6) + (img ^ sw)] = make_uint2(lo.u, hi.u);
    }
    __syncthreads();

    // ---- fc1: wave w8 -> outputs 8*w8..8*w8+7, lanes = 64 images ----
    {
        const int img = tid & 63;
        const int w8  = __builtin_amdgcn_readfirstlane(tid >> 6);
        const float* wbase = fc1_w + (w8 * 8) * 256;

        float a0=0.f,a1=0.f,a2=0.f,a3=0.f,a4=0.f,a5=0.f,a6=0.f,a7=0.f;

        #pragma unroll 2
        for (int kk = 0; kk < 64; ++kk) {
            uint2 hu = hbuf[(kk << 6) + (img ^ (kk & 15))];   // perm-contiguous b64
            h2cvt ua, ub; ua.u = hu.x; ub.u = hu.y;
            float2 f01 = __half22float2(ua.h);
            float2 f23 = __half22float2(ub.h);
            const float* wp = wbase + kk * 4;
            float4 w0 = *(const float4*)(wp + 0 * 256);   // uniform -> s_load
            float4 w1 = *(const float4*)(wp + 1 * 256);
            float4 w2 = *(const float4*)(wp + 2 * 256);
            float4 w3 = *(const float4*)(wp + 3 * 256);
            float4 w4 = *(const float4*)(wp + 4 * 256);
            float4 w5 = *(const float4*)(wp + 5 * 256);
            float4 w6 = *(const float4*)(wp + 6 * 256);
            float4 w7 = *(const float4*)(wp + 7 * 256);
            a0 = fmaf(f01.x,w0.x,a0); a0 = fmaf(f01.y,w0.y,a0); a0 = fmaf(f23.x,w0.z,a0); a0 = fmaf(f23.y,w0.w,a0);
            a1 = fmaf(f01.x,w1.x,a1); a1 = fmaf(f01.y,w1.y,a1); a1 = fmaf(f23.x,w1.z,a1); a1 = fmaf(f23.y,w1.w,a1);
            a2 = fmaf(f01.x,w2.x,a2); a2 = fmaf(f01.y,w2.y,a2); a2 = fmaf(f23.x,w2.z,a2); a2 = fmaf(f23.y,w2.w,a2);
            a3 = fmaf(f01.x,w3.x,a3); a3 = fmaf(f01.y,w3.y,a3); a3 = fmaf(f23.x,w3.z,a3); a3 = fmaf(f23.y,w3.w,a3);
            a4 = fmaf(f01.x,w4.x,a4); a4 = fmaf(f01.y,w4.y,a4); a4 = fmaf(f23.x,w4.z,a4); a4 = fmaf(f23.y,w4.w,a4);
            a5 = fmaf(f01.x,w5.x,a5); a5 = fmaf(f01.y,w5.y,a5); a5 = fmaf(f23.x,w5.z,a5); a5 = fmaf(f23.y,w5.w,a5);
            a6 = fmaf(f01.x,w6.x,a6); a6 = fmaf(f01.y,w6.y,a6); a6 = fmaf(f23.x,w6.z,a6); a6 = fmaf(f23.y,w6.w,a6);
            a7 = fmaf(f01.x,w7.x,a7); a7 = fmaf(f01.y,w7.y,a7); a7 = fmaf(f23.x,w7.z,a7); a7 = fmaf(f23.y,w7.w,a7);
        }

        __syncthreads();   // all conv-phase xbuf use done before h2 aliases it

        const float* bp = fc1_b + w8 * 8;
        float4 p0, p1;
        p0.x = a0 + bp[0]; p0.x *= p0.x;
        p0.y = a1 + bp[1]; p0.y *= p0.y;
        p0.z = a2 + bp[2]; p0.z *= p0.z;
        p0.w = a3 + bp[3]; p0.w *= p0.w;
        p1.x = a4 + bp[4]; p1.x *= p1.x;
        p1.y = a5 + bp[5]; p1.y *= p1.y;
        p1.z = a6 + bp[6]; p1.z *= p1.z;
        p1.w = a7 + bp[7]; p1.w *= p1.w;
        h2b[(w8 * 2 + 0) * 64 + img] = p0;   // lane-contiguous b128
        h2b[(w8 * 2 + 1) * 64 + img] = p1;
    }
    __syncthreads();

    // ---- fc2: thread (im3 = tid>>3, q = tid&7) ----
    {
        const int im3 = tid >> 3;
        const int q   = tid & 7;

        float s1 = 0.f;
        #pragma unroll
        for (int kk = 0; kk < 16; ++kk) {
            float4 hh = h2b[kk * 64 + im3];
            float4 wA = w2b[kk * 16 + q];
            s1 = fmaf(hh.x, wA.x, s1); s1 = fmaf(hh.y, wA.y, s1);
            s1 = fmaf(hh.z, wA.z, s1); s1 = fmaf(hh.w, wA.w, s1);
        }
        float r1 = s1 + fc2_b[q];

        float r2 = 0.f;
        if (q < 2) {
            float s2 = 0.f;
            #pragma unroll
            for (int kk = 0; kk < 16; ++kk) {
                float4 hh = h2b[kk * 64 + im3];
                float4 wB = w2b[kk * 16 + 8 + q];
                s2 = fmaf(hh.x, wB.x, s2); s2 = fmaf(hh.y, wB.y, s2);
                s2 = fmaf(hh.z, wB.z, s2); s2 = fmaf(hh.w, wB.w, s2);
            }
            r2 = s2 + fc2_b[8 + q];
        }
        __syncthreads();               // h2 reads done before ob stores to region
        ob[im3 * 10 + q] = r1;
        if (q < 2) ob[im3 * 10 + 8 + q] = r2;
    }
    __syncthreads();

    // coalesced output store
    if (tid < 160) {
        float4 v = *(const float4*)(ob + tid * 4);
        *(float4*)(out + (long)blk * 640 + tid * 4) = v;
    }
}

extern "C" void kernel_launch(void* const* d_in, const int* in_sizes, int n_in,
                              void* d_out, int out_size, void* d_ws, size_t ws_size,
                              hipStream_t stream) {
    const float* x      = (const float*)d_in[0];
    const float* conv_w = (const float*)d_in[1];
    const float* conv_b = (const float*)d_in[2];
    const float* fc1_w  = (const float*)d_in[3];
    const float* fc1_b  = (const float*)d_in[4];
    const float* fc2_w  = (const float*)d_in[5];
    const float* fc2_b  = (const float*)d_in[6];
    float* out = (float*)d_out;

    const int B = in_sizes[0] / 784;
    const int blocks = (B + BLK_IMGS - 1) / BLK_IMGS;      // 1024 for B=65536
    const size_t lds_bytes = LDS_TOTAL_F * sizeof(float);  // 61952 < 64KB default cap

    encconv_fused4<<<blocks, 512, lds_bytes, stream>>>(
        x, conv_w, conv_b, fc1_w, fc1_b, fc2_w, fc2_b, out);
}